// Round 1
// baseline (102.056 us; speedup 1.0000x reference)
//
#include <hip/hip_runtime.h>

// S4D kernel generation:
//   out[h, l] = 2 * Re( sum_n Ccp[h,n] * w_n^l ),  w_n = exp(dt*A_n),  l = 0..4095
//
// Round-3 structure (latency/occupancy attack; op count already at algorithmic
// floor of 3 VALU ops per (state,l) point):
//  - 1 h per block, 256 threads. STATE-SPLIT: threads 0-127 own states 0-15,
//    threads 128-255 own states 16-31; each thread owns l = lane + 128*i,
//    i = 0..31. Grid 512 -> 1024 blocks => 4 waves/SIMD (was 2). Total
//    transcendental/fp64 setup work is unchanged (each (h,n,lane) once).
//  - EVEN/ODD CHAINS: two independent order-2 recurrences with V = W^2
//    (W = w^128, stride-256 in l). Same op count, half the dependent-FMA
//    critical path. V phase computed directly from the fp64 revolution count
//    (not W^2 in fp32), so accuracy is equal-or-better than round-2.
//  - Cross-half combine through padded LDS [128][33] (worst 2-way bank
//    aliasing = free); each half stores 16 coalesced l-slices.

#define NN  32          // N/2 states
#define LL  4096
#define TPB 256
#define TPH 128         // threads (lanes) per h
#define CH  (LL/TPH)    // 32 l-values per thread
#define NH  16          // states per half

typedef float f32x2 __attribute__((ext_vector_type(2)));

__global__ __launch_bounds__(TPB, 4) void s4d_kernel(
    const float* __restrict__ log_dt,
    const float* __restrict__ C,          // (H, NN, 2) interleaved re/im
    const float* __restrict__ log_A_real, // (H, NN)
    const float* __restrict__ A_imag,     // (H, NN)
    float* __restrict__ out)              // (H, LL)
{
    const int h    = blockIdx.x;
    const int t    = threadIdx.x;
    const int half = t >> 7;      // which state-half
    const int lane = t & (TPH - 1);

    __shared__ float  s_cr[NN], s_ci[NN];     // Ccp = C*(exp(dtA)-1)/A
    __shared__ float  s_dtAre[NN];
    __shared__ double s_rev[NN];              // dt*Aim/(2pi) revolutions per l
    __shared__ float  s_Wr[NN], s_Wi[NN];     // W = w^128
    __shared__ float  s_Vr[NN], s_Vi[NN];     // V = w^256 = W^2 (phase via fp64)
    __shared__ float  s_aV[NN], s_mVn[NN];    // aV = 2Re(V), mVn = -|V|^2
    __shared__ float  s_red[TPH][NN + 1];     // cross-half partial sums (padded)

    if (t < NN) {
        const int n = t;
        const float dt    = __expf(log_dt[h]);
        const float Are   = -__expf(log_A_real[h * NN + n]);
        const float Aim   = A_imag[h * NN + n];
        const float dtAre = dt * Are;
        const float dtAim = dt * Aim;          // |.| <= ~9.8

        // f = (exp(dtA) - 1) / A
        const float e = __expf(dtAre);
        float s, c;
        __sincosf(dtAim, &s, &c);
        const float nre = e * c - 1.0f;
        const float nim = e * s;
        const float inv = 1.0f / (Are * Are + Aim * Aim);
        const float fre = (nre * Are + nim * Aim) * inv;
        const float fim = (nim * Are - nre * Aim) * inv;

        const float Cre = C[(h * NN + n) * 2 + 0];
        const float Cim = C[(h * NN + n) * 2 + 1];
        s_cr[n] = Cre * fre - Cim * fim;
        s_ci[n] = Cre * fim + Cim * fre;
        s_dtAre[n] = dtAre;

        const double rev1 = (double)dt * (double)Aim * 0.15915494309189535; // /(2pi)
        s_rev[n] = rev1;

        // W = w^128: magnitude exact via expf, phase reduced mod 1 rev in fp64
        double rw = rev1 * (double)TPH;
        rw -= floor(rw);
        float sw, cw;
        __sincosf((float)rw * 6.2831853071795864f, &sw, &cw);
        const float ew = __expf(dtAre * (float)TPH);
        s_Wr[n] = ew * cw;
        s_Wi[n] = ew * sw;

        // V = w^256: phase reduced in fp64 directly (better than fp32 W^2)
        double rv2 = rev1 * (double)(2 * TPH);
        rv2 -= floor(rv2);
        float sv, cv;
        __sincosf((float)rv2 * 6.2831853071795864f, &sv, &cv);
        const float ew2 = ew * ew;
        s_Vr[n]  = ew2 * cv;
        s_Vi[n]  = ew2 * sv;
        s_aV[n]  = 2.0f * (ew2 * cv);
        s_mVn[n] = -(ew2 * ew2);               // -|V|^2, exact magnitude
    }
    __syncthreads();

    f32x2 acc[CH];
#pragma unroll
    for (int i = 0; i < CH; ++i) acc[i] = (f32x2){0.0f, 0.0f};

    const float lf    = (float)lane;
    const int   nbase = half * NH;

    for (int j0 = 0; j0 < NH; j0 += 2) {
        const int np = nbase + j0;
        float E0[2], E1[2], O0[2], O1[2];
#pragma unroll
        for (int jj = 0; jj < 2; ++jj) {
            const int n = np + jj;
            // z0 = Ccp * w^lane, phase mod 2pi in fp64
            double rv = s_rev[n] * (double)lane;
            rv -= floor(rv);
            float si, co;
            __sincosf((float)rv * 6.2831853071795864f, &si, &co);
            const float er = __expf(s_dtAre[n] * lf);
            const float zr = er * co, zi = er * si;
            const float cr = s_cr[n], cim = s_ci[n];
            const float xr = cr * zr - cim * zi;   // Re(z0)  -> x_0
            const float xi = cr * zi + cim * zr;   // Im(z0)
            const float Wr = s_Wr[n], Wi = s_Wi[n];
            const float x1r = xr * Wr - xi * Wi;   // Re(z0*W) -> x_1
            const float x1i = xr * Wi + xi * Wr;   // Im(z0*W)
            const float Vr = s_Vr[n], Vi = s_Vi[n];
            E0[jj] = xr;                           // x_0
            E1[jj] = xr * Vr - xi * Vi;            // Re(z0*V)   = x_2
            O0[jj] = x1r;                          // x_1
            O1[jj] = x1r * Vr - x1i * Vi;          // Re(z0*W*V) = x_3
        }
        const f32x2 aV  = { s_aV[np],  s_aV[np + 1] };
        const f32x2 mVn = { s_mVn[np], s_mVn[np + 1] };
        f32x2 e0 = { E0[0], E0[1] }, e1 = { E1[0], E1[1] };  // even chain
        f32x2 o0 = { O0[0], O0[1] }, o1 = { O1[0], O1[1] };  // odd chain
#pragma unroll
        for (int i = 0; i < CH; i += 4) {
            acc[i]     += e0;
            acc[i + 1] += o0;
            acc[i + 2] += e1;
            acc[i + 3] += o1;
            // two independent stride-2 recurrences: y_{m+1} = aV*y_m - |V|^2*y_{m-1}
            e0 = __builtin_elementwise_fma(aV, e1, mVn * e0);  // x_{i+4}
            o0 = __builtin_elementwise_fma(aV, o1, mVn * o0);  // x_{i+5}
            e1 = __builtin_elementwise_fma(aV, e0, mVn * e1);  // x_{i+6}
            o1 = __builtin_elementwise_fma(aV, o0, mVn * o1);  // x_{i+7}
        }
    }

    // Cross-half reduction: each half publishes the 16 l-slices the OTHER half
    // stores, then both halves store 16 coalesced slices each.
    const int io = (1 - half) * NH;   // slices I publish
    const int is = half * NH;         // slices I store
#pragma unroll
    for (int k = 0; k < NH; ++k)
        s_red[lane][io + k] = acc[io + k].x + acc[io + k].y;
    __syncthreads();

    float* o = out + (size_t)h * LL + (size_t)is * TPH + lane;
#pragma unroll
    for (int k = 0; k < NH; ++k)
        o[(size_t)k * TPH] = 2.0f * (acc[is + k].x + acc[is + k].y + s_red[lane][is + k]);
}

extern "C" void kernel_launch(void* const* d_in, const int* in_sizes, int n_in,
                              void* d_out, int out_size, void* d_ws, size_t ws_size,
                              hipStream_t stream) {
    const float* log_dt     = (const float*)d_in[0];
    const float* C          = (const float*)d_in[1];
    const float* log_A_real = (const float*)d_in[2];
    const float* A_imag     = (const float*)d_in[3];
    // d_in[4] is L (device scalar); L=4096 fixed by the problem spec.
    float* out = (float*)d_out;

    const int H = in_sizes[0];  // 1024
    s4d_kernel<<<dim3(H), dim3(TPB), 0, stream>>>(log_dt, C, log_A_real, A_imag, out);
}

// Round 2
// 78.333 us; speedup vs baseline: 1.3029x; 1.3029x over previous
//
#include <hip/hip_runtime.h>

// S4D kernel generation:
//   out[h, l] = 2 * Re( sum_n Ccp[h,n] * w_n^l ),  w_n = exp(dt*A_n),  l = 0..4095
//
// Round-4 structure (occupancy attack without register spill):
//  - 1 h per block, 256 threads, each thread owns l = lane + 256*i, i = 0..15
//    (CH=16). acc[16] f32x2 = 32 VGPRs (was 64 at CH=32). No state split, no
//    cross-half LDS reduction: every thread covers all 32 states via free LDS
//    broadcast reads. Peak live set ~70 VGPRs -> __launch_bounds__(256,6)
//    (VGPR cap 85) => 24 waves/CU = 6 waves/SIMD, 3x the round-2 occupancy.
//  - EVEN/ODD CHAINS kept: two independent order-2 real recurrences with
//    V = w^512 (W = w^256), 3 pk-ops per 2 states per l (algorithmic floor),
//    dependent-FMA critical path 2 per 4 l's, chains only 8 deep.
//  - Phases reduced mod 1 revolution in fp64 (|phase| up to ~800 rev), so
//    sincosf sees small angles; magnitudes via expf directly (exact).

#define NN  32          // N/2 states
#define LL  4096
#define TPB 256         // threads per block = lanes per h
#define CH  (LL/TPB)    // 16 l-values per thread

typedef float f32x2 __attribute__((ext_vector_type(2)));

__global__ __launch_bounds__(TPB, 6) void s4d_kernel(
    const float* __restrict__ log_dt,
    const float* __restrict__ C,          // (H, NN, 2) interleaved re/im
    const float* __restrict__ log_A_real, // (H, NN)
    const float* __restrict__ A_imag,     // (H, NN)
    float* __restrict__ out)              // (H, LL)
{
    const int h    = blockIdx.x;
    const int lane = threadIdx.x;         // 0..255

    __shared__ float  s_cr[NN], s_ci[NN];     // Ccp = C*(exp(dtA)-1)/A
    __shared__ float  s_dtAre[NN];
    __shared__ double s_rev[NN];              // dt*Aim/(2pi) revolutions per l
    __shared__ float  s_Wr[NN], s_Wi[NN];     // W = w^256
    __shared__ float  s_Vr[NN], s_Vi[NN];     // V = w^512 (phase via fp64)
    __shared__ float  s_aV[NN], s_mVn[NN];    // aV = 2Re(V), mVn = -|V|^2

    if (lane < NN) {
        const int n = lane;
        const float dt    = __expf(log_dt[h]);
        const float Are   = -__expf(log_A_real[h * NN + n]);
        const float Aim   = A_imag[h * NN + n];
        const float dtAre = dt * Are;
        const float dtAim = dt * Aim;          // |.| <= ~9.8

        // f = (exp(dtA) - 1) / A
        const float e = __expf(dtAre);
        float s, c;
        __sincosf(dtAim, &s, &c);
        const float nre = e * c - 1.0f;
        const float nim = e * s;
        const float inv = 1.0f / (Are * Are + Aim * Aim);
        const float fre = (nre * Are + nim * Aim) * inv;
        const float fim = (nim * Are - nre * Aim) * inv;

        const float Cre = C[(h * NN + n) * 2 + 0];
        const float Cim = C[(h * NN + n) * 2 + 1];
        s_cr[n] = Cre * fre - Cim * fim;
        s_ci[n] = Cre * fim + Cim * fre;
        s_dtAre[n] = dtAre;

        const double rev1 = (double)dt * (double)Aim * 0.15915494309189535; // /(2pi)
        s_rev[n] = rev1;

        // W = w^256: magnitude exact via expf, phase reduced mod 1 rev in fp64
        double rw = rev1 * (double)TPB;
        rw -= floor(rw);
        float sw, cw;
        __sincosf((float)rw * 6.2831853071795864f, &sw, &cw);
        const float ew = __expf(dtAre * (float)TPB);
        s_Wr[n] = ew * cw;
        s_Wi[n] = ew * sw;

        // V = w^512: phase reduced in fp64 directly (better than fp32 W^2)
        double rv2 = rev1 * (double)(2 * TPB);
        rv2 -= floor(rv2);
        float sv, cv;
        __sincosf((float)rv2 * 6.2831853071795864f, &sv, &cv);
        const float ew2 = ew * ew;
        s_Vr[n]  = ew2 * cv;
        s_Vi[n]  = ew2 * sv;
        s_aV[n]  = 2.0f * (ew2 * cv);
        s_mVn[n] = -(ew2 * ew2);               // -|V|^2, exact magnitude
    }
    __syncthreads();

    f32x2 acc[CH];
#pragma unroll
    for (int i = 0; i < CH; ++i) acc[i] = (f32x2){0.0f, 0.0f};

    const float lf = (float)lane;

    for (int np = 0; np < NN; np += 2) {
        float E0[2], E1[2], O0[2], O1[2];
#pragma unroll
        for (int jj = 0; jj < 2; ++jj) {
            const int n = np + jj;
            // z0 = Ccp * w^lane, phase mod 2pi in fp64
            double rv = s_rev[n] * (double)lane;
            rv -= floor(rv);
            float si, co;
            __sincosf((float)rv * 6.2831853071795864f, &si, &co);
            const float er = __expf(s_dtAre[n] * lf);
            const float zr = er * co, zi = er * si;
            const float cr = s_cr[n], cim = s_ci[n];
            const float xr = cr * zr - cim * zi;    // Re(z0)  -> x_0
            const float xi = cr * zi + cim * zr;    // Im(z0)
            const float Wr = s_Wr[n], Wi = s_Wi[n];
            const float x1r = xr * Wr - xi * Wi;    // Re(z0*W) -> x_1
            const float x1i = xr * Wi + xi * Wr;    // Im(z0*W)
            const float Vr = s_Vr[n], Vi = s_Vi[n];
            E0[jj] = xr;                            // x_0
            E1[jj] = xr * Vr - xi * Vi;             // Re(z0*V)   = x_2
            O0[jj] = x1r;                           // x_1
            O1[jj] = x1r * Vr - x1i * Vi;           // Re(z0*W*V) = x_3
        }
        const f32x2 aV  = { s_aV[np],  s_aV[np + 1] };
        const f32x2 mVn = { s_mVn[np], s_mVn[np + 1] };
        f32x2 e0 = { E0[0], E0[1] }, e1 = { E1[0], E1[1] };  // even chain
        f32x2 o0 = { O0[0], O0[1] }, o1 = { O1[0], O1[1] };  // odd chain
#pragma unroll
        for (int i = 0; i < CH; i += 4) {
            acc[i]     += e0;
            acc[i + 1] += o0;
            acc[i + 2] += e1;
            acc[i + 3] += o1;
            // two independent stride-2 recurrences: y_{m+1} = aV*y_m - |V|^2*y_{m-1}
            e0 = __builtin_elementwise_fma(aV, e1, mVn * e0);  // x_{i+4}
            o0 = __builtin_elementwise_fma(aV, o1, mVn * o0);  // x_{i+5}
            e1 = __builtin_elementwise_fma(aV, e0, mVn * e1);  // x_{i+6}
            o1 = __builtin_elementwise_fma(aV, o0, mVn * o1);  // x_{i+7}
        }
    }

    float* o = out + (size_t)h * LL + lane;
#pragma unroll
    for (int i = 0; i < CH; ++i)
        o[(size_t)i * TPB] = 2.0f * (acc[i].x + acc[i].y);
}

extern "C" void kernel_launch(void* const* d_in, const int* in_sizes, int n_in,
                              void* d_out, int out_size, void* d_ws, size_t ws_size,
                              hipStream_t stream) {
    const float* log_dt     = (const float*)d_in[0];
    const float* C          = (const float*)d_in[1];
    const float* log_A_real = (const float*)d_in[2];
    const float* A_imag     = (const float*)d_in[3];
    // d_in[4] is L (device scalar); L=4096 fixed by the problem spec.
    float* out = (float*)d_out;

    const int H = in_sizes[0];  // 1024
    s4d_kernel<<<dim3(H), dim3(TPB), 0, stream>>>(log_dt, C, log_A_real, A_imag, out);
}

// Round 3
// 75.551 us; speedup vs baseline: 1.3508x; 1.0368x over previous
//
#include <hip/hip_runtime.h>

// S4D kernel generation:
//   out[h, l] = 2 * Re( sum_n Ccp[h,n] * w_n^l ),  w_n = exp(dt*A_n),  l = 0..4095
//
// Round-5 structure (kill the setup transcendentals; occupancy was proven a
// non-lever in rounds 3-4: 2 vs 4 waves/SIMD gave identical time):
//  - Two-level table decomposition of the per-thread starting point:
//       w^lane = w^(lane&15) * w^(16*(lane>>4))
//    Per (h,n) LDS tables: T1[n][j] = Ccp*w^j (j=0..15), T2[n][k] = w^(16k).
//    Table build = 1024 sincos/exp/fp64-mod chains per h (4 per thread) vs
//    8192 in round-4 -- 8x fewer long-latency trans/f64 dependency chains.
//    Main phase z0 = T1*T2: 2 broadcast ds_read_b64 + 12 VALU, no trans/f64.
//  - 1 h per block, 256 threads, CH=16 (acc[16] f32x2 = 32 VGPRs, no spill).
//  - EVEN/ODD CHAINS kept: two independent order-2 real recurrences with
//    V = w^512 (W = w^256), 3 pk-ops per 2 states per l (algorithmic floor).
//  - All phases reduced mod 1 revolution in fp64; magnitudes exact via expf.

#define NN  32          // N/2 states
#define LL  4096
#define TPB 256         // threads per block = lanes per h
#define CH  (LL/TPB)    // 16 l-values per thread

typedef float f32x2 __attribute__((ext_vector_type(2)));

__global__ __launch_bounds__(TPB, 4) void s4d_kernel(
    const float* __restrict__ log_dt,
    const float* __restrict__ C,          // (H, NN, 2) interleaved re/im
    const float* __restrict__ log_A_real, // (H, NN)
    const float* __restrict__ A_imag,     // (H, NN)
    float* __restrict__ out)              // (H, LL)
{
    const int h = blockIdx.x;
    const int t = threadIdx.x;            // 0..255

    __shared__ float  s_cr[NN], s_ci[NN];     // Ccp = C*(exp(dtA)-1)/A
    __shared__ float  s_dtAre[NN];
    __shared__ double s_rev[NN];              // dt*Aim/(2pi) revolutions per l
    __shared__ float  s_Wr[NN], s_Wi[NN];     // W = w^256
    __shared__ float  s_Vr[NN], s_Vi[NN];     // V = w^512 (phase via fp64)
    __shared__ float  s_aV[NN], s_mVn[NN];    // aV = 2Re(V), mVn = -|V|^2
    __shared__ f32x2  s_T1[NN][16];           // Ccp * w^j,  j = 0..15
    __shared__ f32x2  s_T2[NN][16];           // w^(16k),    k = 0..15

    // ---- stage 1: per-state coefficients (32 threads) ----
    if (t < NN) {
        const int n = t;
        const float dt    = __expf(log_dt[h]);
        const float Are   = -__expf(log_A_real[h * NN + n]);
        const float Aim   = A_imag[h * NN + n];
        const float dtAre = dt * Are;
        const float dtAim = dt * Aim;          // |.| <= ~9.8

        // f = (exp(dtA) - 1) / A
        const float e = __expf(dtAre);
        float s, c;
        __sincosf(dtAim, &s, &c);
        const float nre = e * c - 1.0f;
        const float nim = e * s;
        const float inv = 1.0f / (Are * Are + Aim * Aim);
        const float fre = (nre * Are + nim * Aim) * inv;
        const float fim = (nim * Are - nre * Aim) * inv;

        const float Cre = C[(h * NN + n) * 2 + 0];
        const float Cim = C[(h * NN + n) * 2 + 1];
        s_cr[n] = Cre * fre - Cim * fim;
        s_ci[n] = Cre * fim + Cim * fre;
        s_dtAre[n] = dtAre;

        const double rev1 = (double)dt * (double)Aim * 0.15915494309189535; // /(2pi)
        s_rev[n] = rev1;

        // W = w^256: magnitude exact via expf, phase reduced mod 1 rev in fp64
        double rw = rev1 * (double)TPB;
        rw -= floor(rw);
        float sw, cw;
        __sincosf((float)rw * 6.2831853071795864f, &sw, &cw);
        const float ew = __expf(dtAre * (float)TPB);
        s_Wr[n] = ew * cw;
        s_Wi[n] = ew * sw;

        // V = w^512: phase reduced in fp64 directly
        double rv2 = rev1 * (double)(2 * TPB);
        rv2 -= floor(rv2);
        float sv, cv;
        __sincosf((float)rv2 * 6.2831853071795864f, &sv, &cv);
        const float ew2 = ew * ew;
        s_Vr[n]  = ew2 * cv;
        s_Vi[n]  = ew2 * sv;
        s_aV[n]  = 2.0f * (ew2 * cv);
        s_mVn[n] = -(ew2 * ew2);               // -|V|^2, exact magnitude
    }
    __syncthreads();

    // ---- stage 2: build T1/T2 (4 entries per thread, uniform control) ----
#pragma unroll
    for (int rep = 0; rep < 4; ++rep) {
        const int e = t + rep * TPB;          // 0..1023
        const int n = (e >> 4) & (NN - 1);
        const int k = e & 15;
        if (rep < 2) {
            // T1[n][k] = Ccp * w^k    (phase <= ~147 rad before reduction)
            double rv = s_rev[n] * (double)k;
            rv -= floor(rv);
            float si, co;
            __sincosf((float)rv * 6.2831853071795864f, &si, &co);
            const float er = __expf(s_dtAre[n] * (float)k);
            const float zr = er * co, zi = er * si;
            const float cr = s_cr[n], ci = s_ci[n];
            s_T1[n][k] = (f32x2){ cr * zr - ci * zi, cr * zi + ci * zr };
        } else {
            // T2[n][k] = w^(16k)      (phase <= ~2350 rad before reduction)
            const int p = k << 4;
            double rv = s_rev[n] * (double)p;
            rv -= floor(rv);
            float si, co;
            __sincosf((float)rv * 6.2831853071795864f, &si, &co);
            const float er = __expf(s_dtAre[n] * (float)p);
            s_T2[n][k] = (f32x2){ er * co, er * si };
        }
    }
    __syncthreads();

    // ---- stage 3: main accumulation ----
    f32x2 acc[CH];
#pragma unroll
    for (int i = 0; i < CH; ++i) acc[i] = (f32x2){0.0f, 0.0f};

    const int lo16 = t & 15;
    const int hi16 = t >> 4;

    for (int np = 0; np < NN; np += 2) {
        float E0[2], E1[2], O0[2], O1[2];
#pragma unroll
        for (int jj = 0; jj < 2; ++jj) {
            const int n = np + jj;
            // z0 = Ccp * w^t = T1[n][t&15] * T2[n][t>>4]  (no trans, no fp64)
            const f32x2 t1 = s_T1[n][lo16];
            const f32x2 t2 = s_T2[n][hi16];
            const float zr = t1.x * t2.x - t1.y * t2.y;   // Re(z0) -> x_0
            const float zi = t1.x * t2.y + t1.y * t2.x;   // Im(z0)
            const float Wr = s_Wr[n], Wi = s_Wi[n];
            const float x1r = zr * Wr - zi * Wi;          // Re(z0*W) -> x_1
            const float x1i = zr * Wi + zi * Wr;          // Im(z0*W)
            const float Vr = s_Vr[n], Vi = s_Vi[n];
            E0[jj] = zr;                                  // x_0
            E1[jj] = zr * Vr - zi * Vi;                   // Re(z0*V)   = x_2
            O0[jj] = x1r;                                 // x_1
            O1[jj] = x1r * Vr - x1i * Vi;                 // Re(z0*W*V) = x_3
        }
        const f32x2 aV  = { s_aV[np],  s_aV[np + 1] };
        const f32x2 mVn = { s_mVn[np], s_mVn[np + 1] };
        f32x2 e0 = { E0[0], E0[1] }, e1 = { E1[0], E1[1] };  // even chain
        f32x2 o0 = { O0[0], O0[1] }, o1 = { O1[0], O1[1] };  // odd chain
#pragma unroll
        for (int i = 0; i < CH; i += 4) {
            acc[i]     += e0;
            acc[i + 1] += o0;
            acc[i + 2] += e1;
            acc[i + 3] += o1;
            // two independent stride-2 recurrences: y_{m+1} = aV*y_m - |V|^2*y_{m-1}
            e0 = __builtin_elementwise_fma(aV, e1, mVn * e0);  // x_{i+4}
            o0 = __builtin_elementwise_fma(aV, o1, mVn * o0);  // x_{i+5}
            e1 = __builtin_elementwise_fma(aV, e0, mVn * e1);  // x_{i+6}
            o1 = __builtin_elementwise_fma(aV, o0, mVn * o1);  // x_{i+7}
        }
    }

    float* o = out + (size_t)h * LL + t;
#pragma unroll
    for (int i = 0; i < CH; ++i)
        o[(size_t)i * TPB] = 2.0f * (acc[i].x + acc[i].y);
}

extern "C" void kernel_launch(void* const* d_in, const int* in_sizes, int n_in,
                              void* d_out, int out_size, void* d_ws, size_t ws_size,
                              hipStream_t stream) {
    const float* log_dt     = (const float*)d_in[0];
    const float* C          = (const float*)d_in[1];
    const float* log_A_real = (const float*)d_in[2];
    const float* A_imag     = (const float*)d_in[3];
    // d_in[4] is L (device scalar); L=4096 fixed by the problem spec.
    float* out = (float*)d_out;

    const int H = in_sizes[0];  // 1024
    s4d_kernel<<<dim3(H), dim3(TPB), 0, stream>>>(log_dt, C, log_A_real, A_imag, out);
}